// Round 10
// baseline (176.065 us; speedup 1.0000x reference)
//
#include <hip/hip_runtime.h>
#include <math.h>

static constexpr int TPB = 256;

typedef short bf16x8 __attribute__((ext_vector_type(8)));
typedef float f32x4 __attribute__((ext_vector_type(4)));

// float -> bf16 (round-to-nearest-even), finite inputs
__device__ inline unsigned short f2bf(float f) {
    unsigned u = __float_as_uint(f);
    return (unsigned short)((u + 0x7fffu + ((u >> 16) & 1u)) >> 16);
}
__device__ inline float bf2f(unsigned short b) {
    return __uint_as_float(((unsigned)b) << 16);
}

// ---------------- CSR build ----------------

__global__ void k_zero(int* p, int n) {
    int i = blockIdx.x * TPB + threadIdx.x;
    if (i < n) p[i] = 0;
}

// histogram + per-edge position; counters padded to one per 64B line to kill
// per-line atomic serialization (memory-side RMW is 64B granular)
__global__ void k_hist_pos(const int* __restrict__ dst, int* __restrict__ cntp,
                           int* __restrict__ epos, int E) {
    int e = blockIdx.x * TPB + threadIdx.x;
    if (e < E) epos[e] = atomicAdd(&cntp[(size_t)dst[e] << 4], 1);
}

// per-block inclusive scan of cntp (strided) -> rp[i+1]; block totals -> bsum
__global__ void k_scan_block(const int* __restrict__ cntp, int* __restrict__ rp,
                             int* __restrict__ bsum, int n) {
    __shared__ int s[TPB];
    int t = threadIdx.x;
    int i = blockIdx.x * TPB + t;
    int v = (i < n) ? cntp[(size_t)i << 4] : 0;
    s[t] = v;
    __syncthreads();
    for (int off = 1; off < TPB; off <<= 1) {
        int a = (t >= off) ? s[t - off] : 0;
        __syncthreads();
        s[t] += a;
        __syncthreads();
    }
    if (i < n) rp[i + 1] = s[t];
    if (t == TPB - 1) bsum[blockIdx.x] = s[t];
}

// exclusive scan of block sums (nb <= 256)
__global__ void k_scan_top(int* bsum, int nb) {
    __shared__ int s[TPB];
    int t = threadIdx.x;
    int v = (t < nb) ? bsum[t] : 0;
    s[t] = v;
    __syncthreads();
    for (int off = 1; off < TPB; off <<= 1) {
        int a = (t >= off) ? s[t - off] : 0;
        __syncthreads();
        s[t] += a;
        __syncthreads();
    }
    if (t < nb) bsum[t] = s[t] - v;  // exclusive
}

// rp finalize + dinv, fused
__global__ void k_scan_add_prep(int* rp, const int* __restrict__ bsum,
                                const int* __restrict__ cntp,
                                float* __restrict__ dinv, int n) {
    int i = blockIdx.x * TPB + threadIdx.x;
    if (i < n) {
        rp[i + 1] += bsum[i >> 8];
        dinv[i] = rsqrtf(1.0f + (float)cntp[(size_t)i << 4]);
    }
    if (i == 0) rp[0] = 0;
}

// non-atomic scatter: position precomputed by k_hist_pos
__global__ void k_fill_na(const int* __restrict__ src, const int* __restrict__ dst,
                          const int* __restrict__ rp, const int* __restrict__ epos,
                          int* __restrict__ csrc, int E) {
    int e = blockIdx.x * TPB + threadIdx.x;
    if (e < E) csrc[rp[dst[e]] + epos[e]] = src[e];
}

// ---------------- GEMM1 (MFMA): Hb = bf16( (x @ W1) * dinv[row] ) ----------------
// 64-row blocks, 4 waves; wave w computes rows w*16..+15 x all 128 cols.
// LDS: x tile [64][128] bf16 (16KB) + W^T [n=128][k=128] bf16 (32KB), both
// XOR-swizzled (byte ^= (row&7)<<4) on write AND read (T2; rule 21).
// Fragment layouts (mfma_f32_16x16x32_bf16, m89-verified D):
//   A: m=lane&15, k=(lane>>4)*8+j   B: n=lane&15, k=(lane>>4)*8+j
//   D: n=lane&15, m=(lane>>4)*4+reg

__global__ __launch_bounds__(256) void k_gemm1_mfma(const float* __restrict__ x,
                                                    const float* __restrict__ W,
                                                    const float* __restrict__ dinv,
                                                    unsigned short* __restrict__ Hb,
                                                    int n) {
    __shared__ unsigned short xt[64 * 128];    // 16 KB
    __shared__ unsigned short wt[128 * 128];   // 32 KB, transposed: wt[n][k]
    int t = threadIdx.x;
    int row0 = blockIdx.x * 64;

    // stage W^T: thread t handles n = t&127, k-half = (t>>7)*64, 8 groups of 8 k
    {
        int nn = t & 127;
        int kh = (t >> 7) * 64;
        unsigned swz = (unsigned)((nn & 7) << 4);
#pragma unroll
        for (int g = 0; g < 8; ++g) {
            int k0 = kh + g * 8;
            bf16x8 bv;
#pragma unroll
            for (int j = 0; j < 8; ++j)
                bv[j] = (short)f2bf(W[(size_t)(k0 + j) * 128 + nn]);  // coalesced over nn
            unsigned byteoff = ((unsigned)(nn * 256 + k0 * 2)) ^ swz; // 16B-aligned
            *(bf16x8*)((char*)wt + byteoff) = bv;
        }
    }
    // stage x tile: 2048 float4s, thread t handles flat = t + i*256
    {
#pragma unroll
        for (int i = 0; i < 8; ++i) {
            int flat = t + i * 256;
            int r = flat >> 5;   // 0..63
            int k4 = flat & 31;  // float4 index within row
            int gr = row0 + r;
            if (gr > n - 1) gr = n - 1;
            float4 v = *(const float4*)(x + (size_t)gr * 128 + k4 * 4);
            unsigned o0 = (unsigned)f2bf(v.x) | ((unsigned)f2bf(v.y) << 16);
            unsigned o1 = (unsigned)f2bf(v.z) | ((unsigned)f2bf(v.w) << 16);
            uint2 u = make_uint2(o0, o1);
            unsigned byteoff = ((unsigned)(r * 256 + k4 * 8)) ^ ((unsigned)((r & 7) << 4));
            *(uint2*)((char*)xt + byteoff) = u;  // 8B write, swizzle is 16B-granular: ok
        }
    }
    __syncthreads();

    int wv = t >> 6;        // wave 0..3
    int l = t & 63;
    int lm = l & 15;        // A-row / B-col / D-col within tile
    int lk = (l >> 4) * 8;  // k base (8 contiguous)

    // A fragments for this wave's 16 rows, all 4 k-steps
    bf16x8 af[4];
#pragma unroll
    for (int ks = 0; ks < 4; ++ks) {
        int r = wv * 16 + lm;
        unsigned byteoff =
            ((unsigned)(r * 256 + (ks * 32 + lk) * 2)) ^ ((unsigned)((r & 7) << 4));
        af[ks] = *(bf16x8*)((char*)xt + byteoff);
    }

    for (int ct = 0; ct < 8; ++ct) {
        f32x4 acc = {0.f, 0.f, 0.f, 0.f};
#pragma unroll
        for (int ks = 0; ks < 4; ++ks) {
            int nn = ct * 16 + lm;
            unsigned byteoff =
                ((unsigned)(nn * 256 + (ks * 32 + lk) * 2)) ^ ((unsigned)((nn & 7) << 4));
            bf16x8 bfr = *(bf16x8*)((char*)wt + byteoff);
            acc = __builtin_amdgcn_mfma_f32_16x16x32_bf16(af[ks], bfr, acc, 0, 0, 0);
        }
        int mb = (l >> 4) * 4;
#pragma unroll
        for (int r = 0; r < 4; ++r) {
            int grow = row0 + wv * 16 + mb + r;
            if (grow < n) {
                float s = dinv[grow];
                Hb[(size_t)grow * 128 + ct * 16 + lm] = f2bf(acc[r] * s);
            }
        }
    }
}

// ---------------- agg1 + GEMM2 fused ----------------
// h = relu( dinv[i]*(Hb[i] + sum_in Hb[s]) + b1 )  -> LDS
// H2b[i][c] = bf16( (h . W2[:,c]) * dinv[i] ),  H2b rows padded to 64 bf16 (128B)

__global__ __launch_bounds__(256) void k_agg1g2(const unsigned int* __restrict__ Hb32,
                                                const int* __restrict__ rp,
                                                const int* __restrict__ csrc,
                                                const float* __restrict__ dinv,
                                                const float* __restrict__ b1,
                                                const float* __restrict__ W2,
                                                unsigned short* __restrict__ H2b,
                                                int n) {
    __shared__ float W2l[128 * 40];  // 20 KB
    __shared__ float hsh[4][128];    // 2 KB
    int t = threadIdx.x;
    int wv = t >> 6, lane = t & 63;
    int i = blockIdx.x * 4 + wv;

    // stage W2 (f32): 1280 float4s, 5 per thread
    {
        const float4* W4 = (const float4*)W2;
        float4* L4 = (float4*)W2l;
#pragma unroll
        for (int j = 0; j < 5; ++j) L4[t + j * 256] = W4[t + j * 256];
    }

    float di = 0.f;
    if (i < n) {
        di = dinv[i];
        unsigned vself = Hb32[(size_t)i * 64 + lane];
        float s0x = __uint_as_float(vself << 16);
        float s0y = __uint_as_float(vself & 0xffff0000u);
        float s1x = 0.f, s1y = 0.f, s2x = 0.f, s2y = 0.f, s3x = 0.f, s3y = 0.f;
        int e = rp[i], end = rp[i + 1];
        for (; e + 8 <= end; e += 8) {
            int i0 = csrc[e], i1 = csrc[e + 1], i2 = csrc[e + 2], i3 = csrc[e + 3];
            int i4 = csrc[e + 4], i5 = csrc[e + 5], i6 = csrc[e + 6], i7 = csrc[e + 7];
            unsigned v0 = Hb32[(size_t)i0 * 64 + lane];
            unsigned v1 = Hb32[(size_t)i1 * 64 + lane];
            unsigned v2 = Hb32[(size_t)i2 * 64 + lane];
            unsigned v3 = Hb32[(size_t)i3 * 64 + lane];
            unsigned v4 = Hb32[(size_t)i4 * 64 + lane];
            unsigned v5 = Hb32[(size_t)i5 * 64 + lane];
            unsigned v6 = Hb32[(size_t)i6 * 64 + lane];
            unsigned v7 = Hb32[(size_t)i7 * 64 + lane];
            s0x += __uint_as_float(v0 << 16); s0y += __uint_as_float(v0 & 0xffff0000u);
            s1x += __uint_as_float(v1 << 16); s1y += __uint_as_float(v1 & 0xffff0000u);
            s2x += __uint_as_float(v2 << 16); s2y += __uint_as_float(v2 & 0xffff0000u);
            s3x += __uint_as_float(v3 << 16); s3y += __uint_as_float(v3 & 0xffff0000u);
            s0x += __uint_as_float(v4 << 16); s0y += __uint_as_float(v4 & 0xffff0000u);
            s1x += __uint_as_float(v5 << 16); s1y += __uint_as_float(v5 & 0xffff0000u);
            s2x += __uint_as_float(v6 << 16); s2y += __uint_as_float(v6 & 0xffff0000u);
            s3x += __uint_as_float(v7 << 16); s3y += __uint_as_float(v7 & 0xffff0000u);
        }
        for (; e + 2 <= end; e += 2) {
            int i0 = csrc[e], i1 = csrc[e + 1];
            unsigned v0 = Hb32[(size_t)i0 * 64 + lane];
            unsigned v1 = Hb32[(size_t)i1 * 64 + lane];
            s0x += __uint_as_float(v0 << 16); s0y += __uint_as_float(v0 & 0xffff0000u);
            s1x += __uint_as_float(v1 << 16); s1y += __uint_as_float(v1 & 0xffff0000u);
        }
        if (e < end) {
            unsigned v0 = Hb32[(size_t)csrc[e] * 64 + lane];
            s0x += __uint_as_float(v0 << 16); s0y += __uint_as_float(v0 & 0xffff0000u);
        }
        float2 bb = ((const float2*)b1)[lane];
        float2 r;
        r.x = fmaxf(fmaf((s0x + s1x) + (s2x + s3x), di, bb.x), 0.f);
        r.y = fmaxf(fmaf((s0y + s1y) + (s2y + s3y), di, bb.y), 0.f);
        ((float2*)hsh[wv])[lane] = r;
    }
    __syncthreads();

    if (i < n && lane < 40) {
        const float* hr = hsh[wv];
        float acc = 0.f;
#pragma unroll 8
        for (int k = 0; k < 128; ++k) acc = fmaf(hr[k], W2l[k * 40 + lane], acc);
        H2b[(size_t)i * 64 + lane] = f2bf(acc * di);
    }
}

// ---------------- agg2 + bias + log_softmax fused: one wave per node ----------------
// H2b rows padded to 64 bf16 (128B aligned)

__global__ __launch_bounds__(256) void k_agg2(const unsigned short* __restrict__ H2b,
                                              const int* __restrict__ rp,
                                              const int* __restrict__ csrc,
                                              const float* __restrict__ dinv,
                                              const float* __restrict__ b2,
                                              float* __restrict__ out, int n) {
    int i = blockIdx.x * 4 + (threadIdx.x >> 6);
    if (i >= n) return;
    int lane = threadIdx.x & 63;
    int c = lane < 40 ? lane : 39;  // clamp for loads; lanes >=40 masked at the end
    float s0 = bf2f(H2b[(size_t)i * 64 + c]);  // self message
    float s1 = 0.f, s2 = 0.f, s3 = 0.f;
    int e = rp[i], end = rp[i + 1];
    for (; e + 8 <= end; e += 8) {
        int i0 = csrc[e], i1 = csrc[e + 1], i2 = csrc[e + 2], i3 = csrc[e + 3];
        int i4 = csrc[e + 4], i5 = csrc[e + 5], i6 = csrc[e + 6], i7 = csrc[e + 7];
        float v0 = bf2f(H2b[(size_t)i0 * 64 + c]);
        float v1 = bf2f(H2b[(size_t)i1 * 64 + c]);
        float v2 = bf2f(H2b[(size_t)i2 * 64 + c]);
        float v3 = bf2f(H2b[(size_t)i3 * 64 + c]);
        float v4 = bf2f(H2b[(size_t)i4 * 64 + c]);
        float v5 = bf2f(H2b[(size_t)i5 * 64 + c]);
        float v6 = bf2f(H2b[(size_t)i6 * 64 + c]);
        float v7 = bf2f(H2b[(size_t)i7 * 64 + c]);
        s0 += v0; s1 += v1; s2 += v2; s3 += v3;
        s0 += v4; s1 += v5; s2 += v6; s3 += v7;
    }
    for (; e + 2 <= end; e += 2) {
        s0 += bf2f(H2b[(size_t)csrc[e] * 64 + c]);
        s1 += bf2f(H2b[(size_t)csrc[e + 1] * 64 + c]);
    }
    if (e < end) s0 += bf2f(H2b[(size_t)csrc[e] * 64 + c]);
    float di = dinv[i];
    float val = fmaf((s0 + s1) + (s2 + s3), di, b2[c]);
    float m = (lane < 40) ? val : -INFINITY;
#pragma unroll
    for (int off = 32; off; off >>= 1) m = fmaxf(m, __shfl_xor(m, off));
    float ex = (lane < 40) ? expf(val - m) : 0.f;
    float s = ex;
#pragma unroll
    for (int off = 32; off; off >>= 1) s += __shfl_xor(s, off);
    float ls = logf(s);
    if (lane < 40) out[(size_t)i * 40 + lane] = val - m - ls;
}

// ---------------- launch ----------------

extern "C" void kernel_launch(void* const* d_in, const int* in_sizes, int n_in,
                              void* d_out, int out_size, void* d_ws, size_t ws_size,
                              hipStream_t stream) {
    const float* x  = (const float*)d_in[0];
    const int*   ei = (const int*)d_in[1];
    const float* W1 = (const float*)d_in[2];
    const float* b1 = (const float*)d_in[3];
    const float* W2 = (const float*)d_in[4];
    const float* b2 = (const float*)d_in[5];

    int n = in_sizes[0] / 128;
    int E = in_sizes[1] / 2;
    const int* src = ei;
    const int* dst = ei + E;

    float* out = (float*)d_out;

    // workspace layout (4-byte units, 16B-aligned chunks)
    char* wsb = (char*)d_ws;
    size_t off = 0;
    auto alloc = [&](size_t elems4) {
        size_t o = off;
        off += ((elems4 + 3) & ~(size_t)3) * 4;
        return o;
    };
    float* dinv = (float*)(wsb + alloc(n));
    int* cntp   = (int*)(wsb + alloc((size_t)n * 16));  // 64B-padded counters, 3.2 MB
    int* rp     = (int*)(wsb + alloc(n + 1));
    int* bsum   = (int*)(wsb + alloc(256));
    int* epos   = (int*)(wsb + alloc(E));
    int* csrc   = (int*)(wsb + alloc(E));
    unsigned int* Hb32   = (unsigned int*)(wsb + alloc((size_t)n * 64));  // H1' bf16
    unsigned short* H2b  = (unsigned short*)(wsb + alloc((size_t)n * 32)); // H2' bf16, 128B rows

    int nbN = (n + TPB - 1) / TPB;   // must be <= 256 for scan_top (50000/256=196, ok)
    int nbE = (E + TPB - 1) / TPB;

    k_zero<<<(int)(((size_t)n * 16 + TPB - 1) / TPB), TPB, 0, stream>>>(cntp, n * 16);
    k_hist_pos<<<nbE, TPB, 0, stream>>>(dst, cntp, epos, E);
    k_scan_block<<<nbN, TPB, 0, stream>>>(cntp, rp, bsum, n);
    k_scan_top<<<1, TPB, 0, stream>>>(bsum, nbN);
    k_scan_add_prep<<<nbN, TPB, 0, stream>>>(rp, bsum, cntp, dinv, n);
    k_fill_na<<<nbE, TPB, 0, stream>>>(src, dst, rp, epos, csrc, E);

    k_gemm1_mfma<<<(n + 63) / 64, TPB, 0, stream>>>(x, W1, dinv, (unsigned short*)Hb32, n);
    k_agg1g2<<<(n + 3) / 4, TPB, 0, stream>>>(Hb32, rp, csrc, dinv, b1, W2, H2b, n);
    k_agg2<<<(n + 3) / 4, TPB, 0, stream>>>(H2b, rp, csrc, dinv, b2, out, n);
}

// Round 12
// 168.944 us; speedup vs baseline: 1.0422x; 1.0422x over previous
//
#include <hip/hip_runtime.h>
#include <math.h>

static constexpr int TPB = 256;

typedef short bf16x8 __attribute__((ext_vector_type(8)));
typedef float f32x4 __attribute__((ext_vector_type(4)));

// float -> bf16 (round-to-nearest-even), finite inputs
__device__ inline unsigned short f2bf(float f) {
    unsigned u = __float_as_uint(f);
    return (unsigned short)((u + 0x7fffu + ((u >> 16) & 1u)) >> 16);
}
__device__ inline float bf2f(unsigned short b) {
    return __uint_as_float(((unsigned)b) << 16);
}

// ---------------- CSR build ----------------

// zero only the used (64B-strided) counter slots
__global__ void k_zero_cnt(int* cntp, int n) {
    int i = blockIdx.x * TPB + threadIdx.x;
    if (i < n) cntp[(size_t)i << 4] = 0;
}

// histogram + per-edge position; counters padded to one per 64B line
__global__ void k_hist_pos(const int* __restrict__ dst, int* __restrict__ cntp,
                           int* __restrict__ epos, int E) {
    int e = blockIdx.x * TPB + threadIdx.x;
    if (e < E) epos[e] = atomicAdd(&cntp[(size_t)dst[e] << 4], 1);
}

// per-block inclusive scan of cntp (strided) -> rp[i+1]; block totals -> bsum; dinv fused
__global__ void k_scan_block(const int* __restrict__ cntp, int* __restrict__ rp,
                             int* __restrict__ bsum, float* __restrict__ dinv, int n) {
    __shared__ int s[TPB];
    int t = threadIdx.x;
    int i = blockIdx.x * TPB + t;
    int v = (i < n) ? cntp[(size_t)i << 4] : 0;
    if (i < n) dinv[i] = rsqrtf(1.0f + (float)v);
    s[t] = v;
    __syncthreads();
    for (int off = 1; off < TPB; off <<= 1) {
        int a = (t >= off) ? s[t - off] : 0;
        __syncthreads();
        s[t] += a;
        __syncthreads();
    }
    if (i < n) rp[i + 1] = s[t];
    if (t == TPB - 1) bsum[blockIdx.x] = s[t];
}

// exclusive scan of block sums (nb <= 256)
__global__ void k_scan_top(int* bsum, int nb) {
    __shared__ int s[TPB];
    int t = threadIdx.x;
    int v = (t < nb) ? bsum[t] : 0;
    s[t] = v;
    __syncthreads();
    for (int off = 1; off < TPB; off <<= 1) {
        int a = (t >= off) ? s[t - off] : 0;
        __syncthreads();
        s[t] += a;
        __syncthreads();
    }
    if (t < nb) bsum[t] = s[t] - v;  // exclusive
}

// rp finalize
__global__ void k_scan_add(int* rp, const int* __restrict__ bsum, int n) {
    int i = blockIdx.x * TPB + threadIdx.x;
    if (i < n) rp[i + 1] += bsum[i >> 8];
    if (i == 0) rp[0] = 0;
}

// non-atomic scatter: position precomputed by k_hist_pos
__global__ void k_fill_na(const int* __restrict__ src, const int* __restrict__ dst,
                          const int* __restrict__ rp, const int* __restrict__ epos,
                          int* __restrict__ csrc, int E) {
    int e = blockIdx.x * TPB + threadIdx.x;
    if (e < E) csrc[rp[dst[e]] + epos[e]] = src[e];
}

// ---------------- GEMM1 (MFMA): Hb = bf16( (x @ W1) * dinv[row] ) ----------------

__global__ __launch_bounds__(256) void k_gemm1_mfma(const float* __restrict__ x,
                                                    const float* __restrict__ W,
                                                    const float* __restrict__ dinv,
                                                    unsigned short* __restrict__ Hb,
                                                    int n) {
    __shared__ unsigned short xt[64 * 128];    // 16 KB
    __shared__ unsigned short wt[128 * 128];   // 32 KB, transposed: wt[n][k]
    int t = threadIdx.x;
    int row0 = blockIdx.x * 64;

    // stage W^T
    {
        int nn = t & 127;
        int kh = (t >> 7) * 64;
        unsigned swz = (unsigned)((nn & 7) << 4);
#pragma unroll
        for (int g = 0; g < 8; ++g) {
            int k0 = kh + g * 8;
            bf16x8 bv;
#pragma unroll
            for (int j = 0; j < 8; ++j)
                bv[j] = (short)f2bf(W[(size_t)(k0 + j) * 128 + nn]);
            unsigned byteoff = ((unsigned)(nn * 256 + k0 * 2)) ^ swz;
            *(bf16x8*)((char*)wt + byteoff) = bv;
        }
    }
    // stage x tile
    {
#pragma unroll
        for (int i = 0; i < 8; ++i) {
            int flat = t + i * 256;
            int r = flat >> 5;
            int k4 = flat & 31;
            int gr = row0 + r;
            if (gr > n - 1) gr = n - 1;
            float4 v = *(const float4*)(x + (size_t)gr * 128 + k4 * 4);
            unsigned o0 = (unsigned)f2bf(v.x) | ((unsigned)f2bf(v.y) << 16);
            unsigned o1 = (unsigned)f2bf(v.z) | ((unsigned)f2bf(v.w) << 16);
            uint2 u = make_uint2(o0, o1);
            unsigned byteoff = ((unsigned)(r * 256 + k4 * 8)) ^ ((unsigned)((r & 7) << 4));
            *(uint2*)((char*)xt + byteoff) = u;
        }
    }
    __syncthreads();

    int wv = t >> 6;
    int l = t & 63;
    int lm = l & 15;
    int lk = (l >> 4) * 8;

    bf16x8 af[4];
#pragma unroll
    for (int ks = 0; ks < 4; ++ks) {
        int r = wv * 16 + lm;
        unsigned byteoff =
            ((unsigned)(r * 256 + (ks * 32 + lk) * 2)) ^ ((unsigned)((r & 7) << 4));
        af[ks] = *(bf16x8*)((char*)xt + byteoff);
    }

    for (int ct = 0; ct < 8; ++ct) {
        f32x4 acc = {0.f, 0.f, 0.f, 0.f};
#pragma unroll
        for (int ks = 0; ks < 4; ++ks) {
            int nn = ct * 16 + lm;
            unsigned byteoff =
                ((unsigned)(nn * 256 + (ks * 32 + lk) * 2)) ^ ((unsigned)((nn & 7) << 4));
            bf16x8 bfr = *(bf16x8*)((char*)wt + byteoff);
            acc = __builtin_amdgcn_mfma_f32_16x16x32_bf16(af[ks], bfr, acc, 0, 0, 0);
        }
        int mb = (l >> 4) * 4;
#pragma unroll
        for (int r = 0; r < 4; ++r) {
            int grow = row0 + wv * 16 + mb + r;
            if (grow < n) {
                float s = dinv[grow];
                Hb[(size_t)grow * 128 + ct * 16 + lm] = f2bf(acc[r] * s);
            }
        }
    }
}

// ---------------- agg1: h = relu( dinv[i] * (Hb[i] + sum_in Hb[s]) + b1 ) ----------------
// Dual-chunk interleaved gather: two independent edge streams per wave.

__global__ __launch_bounds__(256) void k_agg1(const unsigned int* __restrict__ Hb32,
                                              const int* __restrict__ rp,
                                              const int* __restrict__ csrc,
                                              const float* __restrict__ dinv,
                                              const float* __restrict__ b1,
                                              float* __restrict__ hout, int n) {
    int i = blockIdx.x * 4 + (threadIdx.x >> 6);
    if (i >= n) return;
    int lane = threadIdx.x & 63;
    unsigned vself = Hb32[(size_t)i * 64 + lane];
    float s0x = __uint_as_float(vself << 16);
    float s0y = __uint_as_float(vself & 0xffff0000u);
    float s1x = 0.f, s1y = 0.f, s2x = 0.f, s2y = 0.f, s3x = 0.f, s3y = 0.f;
    int e0 = rp[i], end = rp[i + 1];
    int len = end - e0;
    int half = len >> 1;
    int eA = e0, eAe = e0 + half;   // chunk A
    int eB = eAe, eBe = end;        // chunk B
    // interleaved: 8 gathers in flight from two independent streams
    while (eA + 4 <= eAe && eB + 4 <= eBe) {
        int a0 = csrc[eA], a1 = csrc[eA + 1], a2 = csrc[eA + 2], a3 = csrc[eA + 3];
        int b0 = csrc[eB], b1i = csrc[eB + 1], b2 = csrc[eB + 2], b3 = csrc[eB + 3];
        unsigned v0 = Hb32[(size_t)a0 * 64 + lane];
        unsigned v1 = Hb32[(size_t)a1 * 64 + lane];
        unsigned v2 = Hb32[(size_t)a2 * 64 + lane];
        unsigned v3 = Hb32[(size_t)a3 * 64 + lane];
        unsigned v4 = Hb32[(size_t)b0 * 64 + lane];
        unsigned v5 = Hb32[(size_t)b1i * 64 + lane];
        unsigned v6 = Hb32[(size_t)b2 * 64 + lane];
        unsigned v7 = Hb32[(size_t)b3 * 64 + lane];
        s0x += __uint_as_float(v0 << 16); s0y += __uint_as_float(v0 & 0xffff0000u);
        s1x += __uint_as_float(v1 << 16); s1y += __uint_as_float(v1 & 0xffff0000u);
        s0x += __uint_as_float(v2 << 16); s0y += __uint_as_float(v2 & 0xffff0000u);
        s1x += __uint_as_float(v3 << 16); s1y += __uint_as_float(v3 & 0xffff0000u);
        s2x += __uint_as_float(v4 << 16); s2y += __uint_as_float(v4 & 0xffff0000u);
        s3x += __uint_as_float(v5 << 16); s3y += __uint_as_float(v5 & 0xffff0000u);
        s2x += __uint_as_float(v6 << 16); s2y += __uint_as_float(v6 & 0xffff0000u);
        s3x += __uint_as_float(v7 << 16); s3y += __uint_as_float(v7 & 0xffff0000u);
        eA += 4; eB += 4;
    }
    // tails (each <= 4 iterations of 2, then 1)
    for (; eA + 2 <= eAe; eA += 2) {
        int a0 = csrc[eA], a1 = csrc[eA + 1];
        unsigned v0 = Hb32[(size_t)a0 * 64 + lane];
        unsigned v1 = Hb32[(size_t)a1 * 64 + lane];
        s0x += __uint_as_float(v0 << 16); s0y += __uint_as_float(v0 & 0xffff0000u);
        s1x += __uint_as_float(v1 << 16); s1y += __uint_as_float(v1 & 0xffff0000u);
    }
    if (eA < eAe) {
        unsigned v0 = Hb32[(size_t)csrc[eA] * 64 + lane];
        s0x += __uint_as_float(v0 << 16); s0y += __uint_as_float(v0 & 0xffff0000u);
    }
    for (; eB + 2 <= eBe; eB += 2) {
        int b0 = csrc[eB], b1i = csrc[eB + 1];
        unsigned v0 = Hb32[(size_t)b0 * 64 + lane];
        unsigned v1 = Hb32[(size_t)b1i * 64 + lane];
        s2x += __uint_as_float(v0 << 16); s2y += __uint_as_float(v0 & 0xffff0000u);
        s3x += __uint_as_float(v1 << 16); s3y += __uint_as_float(v1 & 0xffff0000u);
    }
    if (eB < eBe) {
        unsigned v0 = Hb32[(size_t)csrc[eB] * 64 + lane];
        s2x += __uint_as_float(v0 << 16); s2y += __uint_as_float(v0 & 0xffff0000u);
    }
    float di = dinv[i];
    float2 bb = ((const float2*)b1)[lane];
    float2 r;
    r.x = fmaxf(fmaf((s0x + s1x) + (s2x + s3x), di, bb.x), 0.f);
    r.y = fmaxf(fmaf((s0y + s1y) + (s2y + s3y), di, bb.y), 0.f);
    ((float2*)hout)[(size_t)i * 64 + lane] = r;
}

// ---------------- GEMM2: H2b = bf16( (h @ W2) * dinv[row] ), rows padded to 64 ----------------

#define COMP(v, j) ((j) == 0 ? (v).x : ((j) == 1 ? (v).y : ((j) == 2 ? (v).z : (v).w)))

__global__ __launch_bounds__(256) void k_gemm2(const float* __restrict__ h,
                                               const float* __restrict__ W,
                                               const float* __restrict__ dinv,
                                               unsigned short* __restrict__ H2b, int n) {
    __shared__ float Wl[128 * 40];  // 20 KiB
    {
        const float4* W4 = (const float4*)W;
        float4* L4 = (float4*)Wl;
        for (int i = threadIdx.x; i < 128 * 10; i += TPB) L4[i] = W4[i];
    }
    __syncthreads();
    int t = threadIdx.x;
    if (t >= 250) return;
    int cg = t % 10;  // col group: cols cg*4 .. cg*4+3
    int rb = t / 10;
    int r0 = blockIdx.x * 100 + rb * 4;
    if (r0 >= n) return;
    int r1 = min(r0 + 1, n - 1), r2 = min(r0 + 2, n - 1), r3 = min(r0 + 3, n - 1);
    const float* h0 = h + (size_t)r0 * 128;
    const float* h1 = h + (size_t)r1 * 128;
    const float* h2 = h + (size_t)r2 * 128;
    const float* h3 = h + (size_t)r3 * 128;
    float4 a0 = make_float4(0, 0, 0, 0), a1 = a0, a2 = a0, a3 = a0;
    const float4* L4 = (const float4*)Wl;
    for (int k = 0; k < 128; k += 4) {
        float4 xa = *(const float4*)(h0 + k);
        float4 xb = *(const float4*)(h1 + k);
        float4 xc = *(const float4*)(h2 + k);
        float4 xd = *(const float4*)(h3 + k);
#pragma unroll
        for (int j = 0; j < 4; ++j) {
            float4 w = L4[(k + j) * 10 + cg];
            float va = COMP(xa, j), vb = COMP(xb, j), vc = COMP(xc, j), vd = COMP(xd, j);
            a0.x = fmaf(va, w.x, a0.x); a0.y = fmaf(va, w.y, a0.y);
            a0.z = fmaf(va, w.z, a0.z); a0.w = fmaf(va, w.w, a0.w);
            a1.x = fmaf(vb, w.x, a1.x); a1.y = fmaf(vb, w.y, a1.y);
            a1.z = fmaf(vb, w.z, a1.z); a1.w = fmaf(vb, w.w, a1.w);
            a2.x = fmaf(vc, w.x, a2.x); a2.y = fmaf(vc, w.y, a2.y);
            a2.z = fmaf(vc, w.z, a2.z); a2.w = fmaf(vc, w.w, a2.w);
            a3.x = fmaf(vd, w.x, a3.x); a3.y = fmaf(vd, w.y, a3.y);
            a3.z = fmaf(vd, w.z, a3.z); a3.w = fmaf(vd, w.w, a3.w);
        }
    }
    auto store = [&](int r, float4 a) {
        float s = dinv[r];
        ushort4 o;
        o.x = f2bf(a.x * s); o.y = f2bf(a.y * s); o.z = f2bf(a.z * s); o.w = f2bf(a.w * s);
        *(ushort4*)(H2b + (size_t)r * 64 + cg * 4) = o;
    };
    store(r0, a0);
    if (r0 + 1 < n) store(r0 + 1, a1);
    if (r0 + 2 < n) store(r0 + 2, a2);
    if (r0 + 3 < n) store(r0 + 3, a3);
}

// ---------------- agg2 + bias + log_softmax fused: one wave per node ----------------
// H2b rows padded to 64 bf16 (128B aligned)

__global__ __launch_bounds__(256) void k_agg2(const unsigned short* __restrict__ H2b,
                                              const int* __restrict__ rp,
                                              const int* __restrict__ csrc,
                                              const float* __restrict__ dinv,
                                              const float* __restrict__ b2,
                                              float* __restrict__ out, int n) {
    int i = blockIdx.x * 4 + (threadIdx.x >> 6);
    if (i >= n) return;
    int lane = threadIdx.x & 63;
    int c = lane < 40 ? lane : 39;  // clamp for loads; lanes >=40 masked at the end
    float s0 = bf2f(H2b[(size_t)i * 64 + c]);  // self message
    float s1 = 0.f, s2 = 0.f, s3 = 0.f;
    int e = rp[i], end = rp[i + 1];
    for (; e + 8 <= end; e += 8) {
        int i0 = csrc[e], i1 = csrc[e + 1], i2 = csrc[e + 2], i3 = csrc[e + 3];
        int i4 = csrc[e + 4], i5 = csrc[e + 5], i6 = csrc[e + 6], i7 = csrc[e + 7];
        float v0 = bf2f(H2b[(size_t)i0 * 64 + c]);
        float v1 = bf2f(H2b[(size_t)i1 * 64 + c]);
        float v2 = bf2f(H2b[(size_t)i2 * 64 + c]);
        float v3 = bf2f(H2b[(size_t)i3 * 64 + c]);
        float v4 = bf2f(H2b[(size_t)i4 * 64 + c]);
        float v5 = bf2f(H2b[(size_t)i5 * 64 + c]);
        float v6 = bf2f(H2b[(size_t)i6 * 64 + c]);
        float v7 = bf2f(H2b[(size_t)i7 * 64 + c]);
        s0 += v0; s1 += v1; s2 += v2; s3 += v3;
        s0 += v4; s1 += v5; s2 += v6; s3 += v7;
    }
    for (; e + 2 <= end; e += 2) {
        s0 += bf2f(H2b[(size_t)csrc[e] * 64 + c]);
        s1 += bf2f(H2b[(size_t)csrc[e + 1] * 64 + c]);
    }
    if (e < end) s0 += bf2f(H2b[(size_t)csrc[e] * 64 + c]);
    float di = dinv[i];
    float val = fmaf((s0 + s1) + (s2 + s3), di, b2[c]);
    float m = (lane < 40) ? val : -INFINITY;
#pragma unroll
    for (int off = 32; off; off >>= 1) m = fmaxf(m, __shfl_xor(m, off));
    float ex = (lane < 40) ? expf(val - m) : 0.f;
    float s = ex;
#pragma unroll
    for (int off = 32; off; off >>= 1) s += __shfl_xor(s, off);
    float ls = logf(s);
    if (lane < 40) out[(size_t)i * 40 + lane] = val - m - ls;
}

// ---------------- launch ----------------

extern "C" void kernel_launch(void* const* d_in, const int* in_sizes, int n_in,
                              void* d_out, int out_size, void* d_ws, size_t ws_size,
                              hipStream_t stream) {
    const float* x  = (const float*)d_in[0];
    const int*   ei = (const int*)d_in[1];
    const float* W1 = (const float*)d_in[2];
    const float* b1 = (const float*)d_in[3];
    const float* W2 = (const float*)d_in[4];
    const float* b2 = (const float*)d_in[5];

    int n = in_sizes[0] / 128;
    int E = in_sizes[1] / 2;
    const int* src = ei;
    const int* dst = ei + E;

    float* out = (float*)d_out;

    // workspace layout (4-byte units, 16B-aligned chunks)
    char* wsb = (char*)d_ws;
    size_t off = 0;
    auto alloc = [&](size_t elems4) {
        size_t o = off;
        off += ((elems4 + 3) & ~(size_t)3) * 4;
        return o;
    };
    float* dinv = (float*)(wsb + alloc(n));
    int* cntp   = (int*)(wsb + alloc((size_t)n * 16));  // 64B-padded counters
    int* rp     = (int*)(wsb + alloc(n + 1));
    int* bsum   = (int*)(wsb + alloc(256));
    int* epos   = (int*)(wsb + alloc(E));
    int* csrc   = (int*)(wsb + alloc(E));
    unsigned int* Hb32   = (unsigned int*)(wsb + alloc((size_t)n * 64));   // H1' bf16
    float* hout          = (float*)(wsb + alloc((size_t)n * 128));         // relu(h1)
    unsigned short* H2b  = (unsigned short*)(wsb + alloc((size_t)n * 32)); // H2' bf16, 128B rows

    int nbN = (n + TPB - 1) / TPB;   // must be <= 256 for scan_top (50000/256=196, ok)
    int nbE = (E + TPB - 1) / TPB;

    k_zero_cnt<<<nbN, TPB, 0, stream>>>(cntp, n);
    k_hist_pos<<<nbE, TPB, 0, stream>>>(dst, cntp, epos, E);
    k_scan_block<<<nbN, TPB, 0, stream>>>(cntp, rp, bsum, dinv, n);
    k_scan_top<<<1, TPB, 0, stream>>>(bsum, nbN);
    k_scan_add<<<nbN, TPB, 0, stream>>>(rp, bsum, n);
    k_fill_na<<<nbE, TPB, 0, stream>>>(src, dst, rp, epos, csrc, E);

    k_gemm1_mfma<<<(n + 63) / 64, TPB, 0, stream>>>(x, W1, dinv, (unsigned short*)Hb32, n);
    k_agg1<<<(n + 3) / 4, TPB, 0, stream>>>(Hb32, rp, csrc, dinv, b1, hout, n);
    k_gemm2<<<(n + 99) / 100, TPB, 0, stream>>>(hout, W2, dinv, H2b, n);
    k_agg2<<<(n + 3) / 4, TPB, 0, stream>>>(H2b, rp, csrc, dinv, b2, out, n);
}

// Round 13
// 158.196 us; speedup vs baseline: 1.1130x; 1.0679x over previous
//
#include <hip/hip_runtime.h>
#include <math.h>

static constexpr int TPB = 256;

typedef short bf16x8 __attribute__((ext_vector_type(8)));
typedef float f32x4 __attribute__((ext_vector_type(4)));

// float -> bf16 (round-to-nearest-even), finite inputs
__device__ inline unsigned short f2bf(float f) {
    unsigned u = __float_as_uint(f);
    return (unsigned short)((u + 0x7fffu + ((u >> 16) & 1u)) >> 16);
}
__device__ inline float bf2f(unsigned short b) {
    return __uint_as_float(((unsigned)b) << 16);
}

// ---------------- CSR build ----------------

// zero only the used (64B-strided) counter slots
__global__ void k_zero_cnt(int* cntp, int n) {
    int i = blockIdx.x * TPB + threadIdx.x;
    if (i < n) cntp[(size_t)i << 4] = 0;
}

// histogram + per-edge position; counters padded to one per 64B line
__global__ void k_hist_pos(const int* __restrict__ dst, int* __restrict__ cntp,
                           int* __restrict__ epos, int E) {
    int e = blockIdx.x * TPB + threadIdx.x;
    if (e < E) epos[e] = atomicAdd(&cntp[(size_t)dst[e] << 4], 1);
}

// per-block inclusive scan of cntp (strided) -> rp[i+1]; block totals -> bsum; dinv fused
__global__ void k_scan_block(const int* __restrict__ cntp, int* __restrict__ rp,
                             int* __restrict__ bsum, float* __restrict__ dinv, int n) {
    __shared__ int s[TPB];
    int t = threadIdx.x;
    int i = blockIdx.x * TPB + t;
    int v = (i < n) ? cntp[(size_t)i << 4] : 0;
    if (i < n) dinv[i] = rsqrtf(1.0f + (float)v);
    s[t] = v;
    __syncthreads();
    for (int off = 1; off < TPB; off <<= 1) {
        int a = (t >= off) ? s[t - off] : 0;
        __syncthreads();
        s[t] += a;
        __syncthreads();
    }
    if (i < n) rp[i + 1] = s[t];
    if (t == TPB - 1) bsum[blockIdx.x] = s[t];
}

// finalize: block b adds prefix = sum(bsum[0..b)) to its rp range (nb <= 256)
__global__ void k_scan_fin(int* rp, const int* __restrict__ bsum, int n) {
    __shared__ int s[TPB];
    int t = threadIdx.x;
    int b = blockIdx.x;
    s[t] = (t < b) ? bsum[t] : 0;
    __syncthreads();
    for (int off = 1; off < TPB; off <<= 1) {
        int a = (t >= off) ? s[t - off] : 0;
        __syncthreads();
        s[t] += a;
        __syncthreads();
    }
    int prefix = s[TPB - 1];
    int i = b * TPB + t;
    if (i < n) rp[i + 1] += prefix;
    if (i == 0) rp[0] = 0;
}

// ---------------- FAT: gemm1 (MFMA) blocks [0,GB) || CSR fill blocks [GB, ...) ----------------
// gemm1: Hb = bf16( (x @ W1) * dinv[row] ), 64-row blocks, 4 waves.
// W^T staged in LDS (32 KB, XOR-swizzled both sides); A-fragments loaded
// directly from global x (2 lanes per 64B line, all bytes used).
// fill: non-atomic scatter csrc[rp[dst]+epos] = src.

__global__ __launch_bounds__(256) void k_fat(const float* __restrict__ x,
                                             const float* __restrict__ W,
                                             const float* __restrict__ dinv,
                                             unsigned short* __restrict__ Hb, int n,
                                             const int* __restrict__ src,
                                             const int* __restrict__ dst,
                                             const int* __restrict__ rp,
                                             const int* __restrict__ epos,
                                             int* __restrict__ csrc, int E, int GB) {
    __shared__ unsigned short wt[128 * 128];  // 32 KB, transposed: wt[n][k]
    int t = threadIdx.x;
    if ((int)blockIdx.x >= GB) {
        // ---- fill branch ----
        int e = ((int)blockIdx.x - GB) * TPB + t;
        if (e < E) csrc[rp[dst[e]] + epos[e]] = src[e];
        return;
    }
    // ---- gemm branch ----
    int row0 = blockIdx.x * 64;

    // stage W^T: thread t handles n = t&127, k-half = (t>>7)*64, 8 groups of 8 k
    {
        int nn = t & 127;
        int kh = (t >> 7) * 64;
        unsigned swz = (unsigned)((nn & 7) << 4);
#pragma unroll
        for (int g = 0; g < 8; ++g) {
            int k0 = kh + g * 8;
            bf16x8 bv;
#pragma unroll
            for (int j = 0; j < 8; ++j)
                bv[j] = (short)f2bf(W[(size_t)(k0 + j) * 128 + nn]);  // coalesced over nn
            unsigned byteoff = ((unsigned)(nn * 256 + k0 * 2)) ^ swz;
            *(bf16x8*)((char*)wt + byteoff) = bv;
        }
    }

    int wv = t >> 6;        // wave 0..3
    int l = t & 63;
    int lm = l & 15;        // A-row / B-col / D-col within tile
    int lk = (l >> 4) * 8;  // k base (8 contiguous)

    // A fragments straight from global x (bf16-convert in regs)
    bf16x8 af[4];
    {
        int grow = row0 + wv * 16 + lm;
        int gr = grow > n - 1 ? n - 1 : grow;
        const float* xr = x + (size_t)gr * 128;
#pragma unroll
        for (int ks = 0; ks < 4; ++ks) {
            float4 p = *(const float4*)(xr + ks * 32 + lk);
            float4 q = *(const float4*)(xr + ks * 32 + lk + 4);
            bf16x8 a;
            a[0] = (short)f2bf(p.x); a[1] = (short)f2bf(p.y);
            a[2] = (short)f2bf(p.z); a[3] = (short)f2bf(p.w);
            a[4] = (short)f2bf(q.x); a[5] = (short)f2bf(q.y);
            a[6] = (short)f2bf(q.z); a[7] = (short)f2bf(q.w);
            af[ks] = a;
        }
    }
    __syncthreads();

    for (int ct = 0; ct < 8; ++ct) {
        f32x4 acc = {0.f, 0.f, 0.f, 0.f};
#pragma unroll
        for (int ks = 0; ks < 4; ++ks) {
            int nn = ct * 16 + lm;
            unsigned byteoff =
                ((unsigned)(nn * 256 + (ks * 32 + lk) * 2)) ^ ((unsigned)((nn & 7) << 4));
            bf16x8 bfr = *(bf16x8*)((char*)wt + byteoff);
            acc = __builtin_amdgcn_mfma_f32_16x16x32_bf16(af[ks], bfr, acc, 0, 0, 0);
        }
        int mb = (l >> 4) * 4;
#pragma unroll
        for (int r = 0; r < 4; ++r) {
            int grow = row0 + wv * 16 + mb + r;
            if (grow < n) {
                float s = dinv[grow];
                Hb[(size_t)grow * 128 + ct * 16 + lm] = f2bf(acc[r] * s);
            }
        }
    }
}

// ---------------- agg1: h = relu( dinv[i] * (Hb[i] + sum_in Hb[s]) + b1 ) ----------------
// Hb rows are 128 bf16 = 64 uint32; lane handles features 2*lane, 2*lane+1.

__global__ __launch_bounds__(256) void k_agg1(const unsigned int* __restrict__ Hb32,
                                              const int* __restrict__ rp,
                                              const int* __restrict__ csrc,
                                              const float* __restrict__ dinv,
                                              const float* __restrict__ b1,
                                              float* __restrict__ hout, int n) {
    int i = blockIdx.x * 4 + (threadIdx.x >> 6);
    if (i >= n) return;
    int lane = threadIdx.x & 63;
    unsigned vself = Hb32[(size_t)i * 64 + lane];
    float s0x = __uint_as_float(vself << 16);
    float s0y = __uint_as_float(vself & 0xffff0000u);
    float s1x = 0.f, s1y = 0.f, s2x = 0.f, s2y = 0.f, s3x = 0.f, s3y = 0.f;
    int e = rp[i], end = rp[i + 1];
    for (; e + 8 <= end; e += 8) {
        int i0 = csrc[e], i1 = csrc[e + 1], i2 = csrc[e + 2], i3 = csrc[e + 3];
        int i4 = csrc[e + 4], i5 = csrc[e + 5], i6 = csrc[e + 6], i7 = csrc[e + 7];
        unsigned v0 = Hb32[(size_t)i0 * 64 + lane];
        unsigned v1 = Hb32[(size_t)i1 * 64 + lane];
        unsigned v2 = Hb32[(size_t)i2 * 64 + lane];
        unsigned v3 = Hb32[(size_t)i3 * 64 + lane];
        unsigned v4 = Hb32[(size_t)i4 * 64 + lane];
        unsigned v5 = Hb32[(size_t)i5 * 64 + lane];
        unsigned v6 = Hb32[(size_t)i6 * 64 + lane];
        unsigned v7 = Hb32[(size_t)i7 * 64 + lane];
        s0x += __uint_as_float(v0 << 16); s0y += __uint_as_float(v0 & 0xffff0000u);
        s1x += __uint_as_float(v1 << 16); s1y += __uint_as_float(v1 & 0xffff0000u);
        s2x += __uint_as_float(v2 << 16); s2y += __uint_as_float(v2 & 0xffff0000u);
        s3x += __uint_as_float(v3 << 16); s3y += __uint_as_float(v3 & 0xffff0000u);
        s0x += __uint_as_float(v4 << 16); s0y += __uint_as_float(v4 & 0xffff0000u);
        s1x += __uint_as_float(v5 << 16); s1y += __uint_as_float(v5 & 0xffff0000u);
        s2x += __uint_as_float(v6 << 16); s2y += __uint_as_float(v6 & 0xffff0000u);
        s3x += __uint_as_float(v7 << 16); s3y += __uint_as_float(v7 & 0xffff0000u);
    }
    for (; e + 2 <= end; e += 2) {
        int i0 = csrc[e], i1 = csrc[e + 1];
        unsigned v0 = Hb32[(size_t)i0 * 64 + lane];
        unsigned v1 = Hb32[(size_t)i1 * 64 + lane];
        s0x += __uint_as_float(v0 << 16); s0y += __uint_as_float(v0 & 0xffff0000u);
        s1x += __uint_as_float(v1 << 16); s1y += __uint_as_float(v1 & 0xffff0000u);
    }
    if (e < end) {
        unsigned v0 = Hb32[(size_t)csrc[e] * 64 + lane];
        s0x += __uint_as_float(v0 << 16); s0y += __uint_as_float(v0 & 0xffff0000u);
    }
    float di = dinv[i];
    float2 bb = ((const float2*)b1)[lane];
    float2 r;
    r.x = fmaxf(fmaf((s0x + s1x) + (s2x + s3x), di, bb.x), 0.f);
    r.y = fmaxf(fmaf((s0y + s1y) + (s2y + s3y), di, bb.y), 0.f);
    ((float2*)hout)[(size_t)i * 64 + lane] = r;
}

// ---------------- GEMM2: H2b = bf16( (h @ W2) * dinv[row] ), rows padded to 64 ----------------

#define COMP(v, j) ((j) == 0 ? (v).x : ((j) == 1 ? (v).y : ((j) == 2 ? (v).z : (v).w)))

__global__ __launch_bounds__(256) void k_gemm2(const float* __restrict__ h,
                                               const float* __restrict__ W,
                                               const float* __restrict__ dinv,
                                               unsigned short* __restrict__ H2b, int n) {
    __shared__ float Wl[128 * 40];  // 20 KiB
    {
        const float4* W4 = (const float4*)W;
        float4* L4 = (float4*)Wl;
        for (int i = threadIdx.x; i < 128 * 10; i += TPB) L4[i] = W4[i];
    }
    __syncthreads();
    int t = threadIdx.x;
    if (t >= 250) return;
    int cg = t % 10;  // col group: cols cg*4 .. cg*4+3
    int rb = t / 10;
    int r0 = blockIdx.x * 100 + rb * 4;
    if (r0 >= n) return;
    int r1 = min(r0 + 1, n - 1), r2 = min(r0 + 2, n - 1), r3 = min(r0 + 3, n - 1);
    const float* h0 = h + (size_t)r0 * 128;
    const float* h1 = h + (size_t)r1 * 128;
    const float* h2 = h + (size_t)r2 * 128;
    const float* h3 = h + (size_t)r3 * 128;
    float4 a0 = make_float4(0, 0, 0, 0), a1 = a0, a2 = a0, a3 = a0;
    const float4* L4 = (const float4*)Wl;
    for (int k = 0; k < 128; k += 4) {
        float4 xa = *(const float4*)(h0 + k);
        float4 xb = *(const float4*)(h1 + k);
        float4 xc = *(const float4*)(h2 + k);
        float4 xd = *(const float4*)(h3 + k);
#pragma unroll
        for (int j = 0; j < 4; ++j) {
            float4 w = L4[(k + j) * 10 + cg];
            float va = COMP(xa, j), vb = COMP(xb, j), vc = COMP(xc, j), vd = COMP(xd, j);
            a0.x = fmaf(va, w.x, a0.x); a0.y = fmaf(va, w.y, a0.y);
            a0.z = fmaf(va, w.z, a0.z); a0.w = fmaf(va, w.w, a0.w);
            a1.x = fmaf(vb, w.x, a1.x); a1.y = fmaf(vb, w.y, a1.y);
            a1.z = fmaf(vb, w.z, a1.z); a1.w = fmaf(vb, w.w, a1.w);
            a2.x = fmaf(vc, w.x, a2.x); a2.y = fmaf(vc, w.y, a2.y);
            a2.z = fmaf(vc, w.z, a2.z); a2.w = fmaf(vc, w.w, a2.w);
            a3.x = fmaf(vd, w.x, a3.x); a3.y = fmaf(vd, w.y, a3.y);
            a3.z = fmaf(vd, w.z, a3.z); a3.w = fmaf(vd, w.w, a3.w);
        }
    }
    auto store = [&](int r, float4 a) {
        float s = dinv[r];
        ushort4 o;
        o.x = f2bf(a.x * s); o.y = f2bf(a.y * s); o.z = f2bf(a.z * s); o.w = f2bf(a.w * s);
        *(ushort4*)(H2b + (size_t)r * 64 + cg * 4) = o;
    };
    store(r0, a0);
    if (r0 + 1 < n) store(r0 + 1, a1);
    if (r0 + 2 < n) store(r0 + 2, a2);
    if (r0 + 3 < n) store(r0 + 3, a3);
}

// ---------------- agg2 + bias + log_softmax fused: one wave per node ----------------
// H2b rows padded to 64 bf16 (128B aligned)

__global__ __launch_bounds__(256) void k_agg2(const unsigned short* __restrict__ H2b,
                                              const int* __restrict__ rp,
                                              const int* __restrict__ csrc,
                                              const float* __restrict__ dinv,
                                              const float* __restrict__ b2,
                                              float* __restrict__ out, int n) {
    int i = blockIdx.x * 4 + (threadIdx.x >> 6);
    if (i >= n) return;
    int lane = threadIdx.x & 63;
    int c = lane < 40 ? lane : 39;  // clamp for loads; lanes >=40 masked at the end
    float s0 = bf2f(H2b[(size_t)i * 64 + c]);  // self message
    float s1 = 0.f, s2 = 0.f, s3 = 0.f;
    int e = rp[i], end = rp[i + 1];
    for (; e + 8 <= end; e += 8) {
        int i0 = csrc[e], i1 = csrc[e + 1], i2 = csrc[e + 2], i3 = csrc[e + 3];
        int i4 = csrc[e + 4], i5 = csrc[e + 5], i6 = csrc[e + 6], i7 = csrc[e + 7];
        float v0 = bf2f(H2b[(size_t)i0 * 64 + c]);
        float v1 = bf2f(H2b[(size_t)i1 * 64 + c]);
        float v2 = bf2f(H2b[(size_t)i2 * 64 + c]);
        float v3 = bf2f(H2b[(size_t)i3 * 64 + c]);
        float v4 = bf2f(H2b[(size_t)i4 * 64 + c]);
        float v5 = bf2f(H2b[(size_t)i5 * 64 + c]);
        float v6 = bf2f(H2b[(size_t)i6 * 64 + c]);
        float v7 = bf2f(H2b[(size_t)i7 * 64 + c]);
        s0 += v0; s1 += v1; s2 += v2; s3 += v3;
        s0 += v4; s1 += v5; s2 += v6; s3 += v7;
    }
    for (; e + 2 <= end; e += 2) {
        s0 += bf2f(H2b[(size_t)csrc[e] * 64 + c]);
        s1 += bf2f(H2b[(size_t)csrc[e + 1] * 64 + c]);
    }
    if (e < end) s0 += bf2f(H2b[(size_t)csrc[e] * 64 + c]);
    float di = dinv[i];
    float val = fmaf((s0 + s1) + (s2 + s3), di, b2[c]);
    float m = (lane < 40) ? val : -INFINITY;
#pragma unroll
    for (int off = 32; off; off >>= 1) m = fmaxf(m, __shfl_xor(m, off));
    float ex = (lane < 40) ? expf(val - m) : 0.f;
    float s = ex;
#pragma unroll
    for (int off = 32; off; off >>= 1) s += __shfl_xor(s, off);
    float ls = logf(s);
    if (lane < 40) out[(size_t)i * 40 + lane] = val - m - ls;
}

// ---------------- launch ----------------

extern "C" void kernel_launch(void* const* d_in, const int* in_sizes, int n_in,
                              void* d_out, int out_size, void* d_ws, size_t ws_size,
                              hipStream_t stream) {
    const float* x  = (const float*)d_in[0];
    const int*   ei = (const int*)d_in[1];
    const float* W1 = (const float*)d_in[2];
    const float* b1 = (const float*)d_in[3];
    const float* W2 = (const float*)d_in[4];
    const float* b2 = (const float*)d_in[5];

    int n = in_sizes[0] / 128;
    int E = in_sizes[1] / 2;
    const int* src = ei;
    const int* dst = ei + E;

    float* out = (float*)d_out;

    // workspace layout (4-byte units, 16B-aligned chunks)
    char* wsb = (char*)d_ws;
    size_t off = 0;
    auto alloc = [&](size_t elems4) {
        size_t o = off;
        off += ((elems4 + 3) & ~(size_t)3) * 4;
        return o;
    };
    float* dinv = (float*)(wsb + alloc(n));
    int* cntp   = (int*)(wsb + alloc((size_t)n * 16));  // 64B-padded counters
    int* rp     = (int*)(wsb + alloc(n + 1));
    int* bsum   = (int*)(wsb + alloc(256));
    int* epos   = (int*)(wsb + alloc(E));
    int* csrc   = (int*)(wsb + alloc(E));
    unsigned int* Hb32   = (unsigned int*)(wsb + alloc((size_t)n * 64));   // H1' bf16
    float* hout          = (float*)(wsb + alloc((size_t)n * 128));         // relu(h1)
    unsigned short* H2b  = (unsigned short*)(wsb + alloc((size_t)n * 32)); // H2' bf16, 128B rows

    int nbN = (n + TPB - 1) / TPB;   // must be <= 256 for scan_fin (50000/256=196, ok)
    int nbE = (E + TPB - 1) / TPB;
    int GB  = (n + 63) / 64;         // gemm1 blocks in the fat kernel

    k_zero_cnt<<<nbN, TPB, 0, stream>>>(cntp, n);
    k_hist_pos<<<nbE, TPB, 0, stream>>>(dst, cntp, epos, E);
    k_scan_block<<<nbN, TPB, 0, stream>>>(cntp, rp, bsum, dinv, n);
    k_scan_fin<<<nbN, TPB, 0, stream>>>(rp, bsum, n);

    k_fat<<<GB + nbE, TPB, 0, stream>>>(x, W1, dinv, (unsigned short*)Hb32, n,
                                        src, dst, rp, epos, csrc, E, GB);

    k_agg1<<<(n + 3) / 4, TPB, 0, stream>>>(Hb32, rp, csrc, dinv, b1, hout, n);
    k_gemm2<<<(n + 99) / 100, TPB, 0, stream>>>(hout, W2, dinv, H2b, n);
    k_agg2<<<(n + 3) / 4, TPB, 0, stream>>>(H2b, rp, csrc, dinv, b2, out, n);
}